// Round 5
// baseline (724.736 us; speedup 1.0000x reference)
//
#include <hip/hip_runtime.h>
#include <math.h>

// Problem constants (fixed by the reference)
#define BN_TOTAL (32 * 4096)   // B*N = 131072 queries
#define DIM 128
#define KPROTO 512
#define EPS 1e-12f
#define MARGIN 1e-4f           // fp32 top-2 gap below this -> fp64 refine
#define REF_CAP 65536          // refine-list capacity (expect ~1-3k)

// ---- workspace layout (d_ws) ----------------------------------------------
// [0..3]        int    refine counter
// [64..262207]  float  pn[512*128]        normalized prototypes (fp32)
// [262208..266303] double ipn[512]        fp64 inverse proto norms
// [266304..528447] int  rlist[65536]      flagged query ids
#define WS_PN_OFF    64
#define WS_IPN_OFF   (WS_PN_OFF + KPROTO * DIM * 4)
#define WS_RL_OFF    (WS_IPN_OFF + KPROTO * 8)

// ---------------------------------------------------------------------------
// Kernel A: normalize prototypes (fp64 norm), store fp64 inv-norms, zero cnt.
// 512 blocks x 64 threads (1 wave). Lane l handles elements l and l+64.
// ---------------------------------------------------------------------------
__global__ __launch_bounds__(64) void proto_norm_kernel(
    const float* __restrict__ protos,   // [512][128]
    float* __restrict__ pn,             // [512][128] normalized fp32
    double* __restrict__ ipn,           // [512] fp64 inverse norms
    int* __restrict__ cnt)
{
    const int k    = blockIdx.x;
    const int lane = threadIdx.x;

    if (k == 0 && lane == 0) *cnt = 0;   // zero refine counter every call

    const float a = protos[k * DIM + lane];
    const float b = protos[k * DIM + lane + 64];
    double s = (double)a * a + (double)b * b;

    #pragma unroll
    for (int off = 32; off >= 1; off >>= 1)
        s += __shfl_xor(s, off, 64);

    const double inv = 1.0 / fmax(sqrt(s), (double)EPS);
    if (lane == 0) ipn[k] = inv;

    pn[k * DIM + lane]      = (float)((double)a * inv);
    pn[k * DIM + lane + 64] = (float)((double)b * inv);
}

// ---------------------------------------------------------------------------
// Kernel B: one thread per query; fp32 scan with top-2 tracking.
// Near-ties (gap <= MARGIN) get flagged for fp64 refinement.
// ---------------------------------------------------------------------------
__global__ __launch_bounds__(256) void assign_kernel(
    const float* __restrict__ x,      // [131072][128]
    const float* __restrict__ pn,     // [512][128] normalized (d_ws)
    const float* __restrict__ praw,   // [512][128] original prototypes
    float* __restrict__ outC,         // [131072][128] cluster centers
    float* __restrict__ outA,         // [131072] assignments (as float)
    int* __restrict__ cnt,
    int* __restrict__ rlist)
{
    const int q = blockIdx.x * 256 + threadIdx.x;

    const float4* xr4 = (const float4*)(x + (size_t)q * DIM);
    float4 xr[32];
    #pragma unroll
    for (int j = 0; j < 32; ++j) xr[j] = xr4[j];

    float s0 = 0.f, s1 = 0.f, s2 = 0.f, s3 = 0.f;
    #pragma unroll
    for (int j = 0; j < 32; ++j) {
        s0 = fmaf(xr[j].x, xr[j].x, s0);
        s1 = fmaf(xr[j].y, xr[j].y, s1);
        s2 = fmaf(xr[j].z, xr[j].z, s2);
        s3 = fmaf(xr[j].w, xr[j].w, s3);
    }
    const float nrm   = sqrtf((s0 + s1) + (s2 + s3));
    const float denom = fmaxf(nrm, EPS);
    #pragma unroll
    for (int j = 0; j < 32; ++j) {
        xr[j].x /= denom;
        xr[j].y /= denom;
        xr[j].z /= denom;
        xr[j].w /= denom;
    }

    float best = -2.0f, best2 = -2.0f;
    int   bidx = 0;
    #pragma unroll 2
    for (int k = 0; k < KPROTO; ++k) {
        const float4* pk = (const float4*)(pn + (size_t)k * DIM);
        float a0 = 0.f, a1 = 0.f, a2 = 0.f, a3 = 0.f;
        #pragma unroll
        for (int j = 0; j < 32; ++j) {
            const float4 p = pk[j];   // wave-uniform -> s_load
            a0 = fmaf(xr[j].x, p.x, a0);
            a1 = fmaf(xr[j].y, p.y, a1);
            a2 = fmaf(xr[j].z, p.z, a2);
            a3 = fmaf(xr[j].w, p.w, a3);
        }
        const float dot = (a0 + a1) + (a2 + a3);
        if (dot > best) { best2 = best; best = dot; bidx = k; }
        else if (dot > best2) { best2 = dot; }
    }

    // near-tie -> flag for fp64 refinement
    if (best - best2 <= MARGIN) {
        const int slot = atomicAdd(cnt, 1);
        if (slot < REF_CAP) rlist[slot] = q;
    }

    const float4* pr = (const float4*)(praw + (size_t)bidx * DIM);
    float4*       oc = (float4*)(outC + (size_t)q * DIM);
    #pragma unroll
    for (int j = 0; j < 32; ++j) oc[j] = pr[j];
    outA[q] = (float)bidx;
}

// ---------------------------------------------------------------------------
// Kernel C: fp64-exact argmax for flagged queries. 1 wave per query,
// 8 protos per lane, wave argmax-reduce with min-index tie-break.
// ---------------------------------------------------------------------------
__global__ __launch_bounds__(64) void refine_kernel(
    const float* __restrict__ x,
    const float* __restrict__ praw,
    const double* __restrict__ ipn,
    const int* __restrict__ cnt,
    const int* __restrict__ rlist,
    float* __restrict__ outC,
    float* __restrict__ outA)
{
    __shared__ double xn[DIM];
    const int lane = threadIdx.x;
    int n = *cnt;
    if (n > REF_CAP) n = REF_CAP;

    for (int i = blockIdx.x; i < n; i += gridDim.x) {
        const int q = rlist[i];

        const double a = (double)x[(size_t)q * DIM + lane];
        const double b = (double)x[(size_t)q * DIM + lane + 64];
        double s = a * a + b * b;
        #pragma unroll
        for (int off = 32; off >= 1; off >>= 1)
            s += __shfl_xor(s, off, 64);
        const double inv = 1.0 / fmax(sqrt(s), (double)EPS);
        xn[lane]      = a * inv;
        xn[lane + 64] = b * inv;
        __syncthreads();

        double bv = -3.0;
        int    bi = 0;
        #pragma unroll
        for (int kk = 0; kk < 8; ++kk) {
            const int k = lane + kk * 64;   // ascending -> strict > keeps first
            const float* pr = praw + (size_t)k * DIM;
            double acc = 0.0;
            for (int d = 0; d < DIM; ++d)
                acc += (double)pr[d] * xn[d];
            const double sim = acc * ipn[k];
            if (sim > bv) { bv = sim; bi = k; }
        }
        #pragma unroll
        for (int off = 32; off >= 1; off >>= 1) {
            const double ov = __shfl_xor(bv, off, 64);
            const int    oi = __shfl_xor(bi, off, 64);
            if (ov > bv || (ov == bv && oi < bi)) { bv = ov; bi = oi; }
        }

        outC[(size_t)q * DIM + lane]      = praw[(size_t)bi * DIM + lane];
        outC[(size_t)q * DIM + lane + 64] = praw[(size_t)bi * DIM + lane + 64];
        if (lane == 0) outA[q] = (float)bi;
        __syncthreads();   // protect xn before next list entry
    }
}

// ---------------------------------------------------------------------------
extern "C" void kernel_launch(void* const* d_in, const int* in_sizes, int n_in,
                              void* d_out, int out_size, void* d_ws, size_t ws_size,
                              hipStream_t stream)
{
    const float* x      = (const float*)d_in[0];   // (32,4096,128) fp32
    const float* protos = (const float*)d_in[1];   // (512,128) fp32

    float* outC = (float*)d_out;
    float* outA = outC + (size_t)BN_TOTAL * DIM;

    int*    cnt   = (int*)d_ws;
    float*  pn    = (float*)((char*)d_ws + WS_PN_OFF);
    double* ipn   = (double*)((char*)d_ws + WS_IPN_OFF);
    int*    rlist = (int*)((char*)d_ws + WS_RL_OFF);

    proto_norm_kernel<<<KPROTO, 64, 0, stream>>>(protos, pn, ipn, cnt);
    assign_kernel<<<BN_TOTAL / 256, 256, 0, stream>>>(x, pn, protos, outC, outA,
                                                      cnt, rlist);
    refine_kernel<<<256, 64, 0, stream>>>(x, protos, ipn, cnt, rlist, outC, outA);
}